// Round 1
// baseline (285.431 us; speedup 1.0000x reference)
//
#include <hip/hip_runtime.h>

#define TOPK 10
#define BLK 256
#define ROWS_PER_BLOCK 8
#define MAXM 2048

__device__ __forceinline__ bool better(float v1, int i1, float v2, int i2) {
    // top_k order: larger value first; ties broken by smaller flat index
    return (v1 > v2) || (v1 == v2 && i1 < i2);
}

__device__ __forceinline__ void insert10(float (&lv)[TOPK], int (&li)[TOPK],
                                         float v, int ix, float& mv, int& mi) {
    // replace current worst slot, then recompute worst. All indices compile-time
    // (unrolled) so arrays stay in VGPRs (rule: no runtime-indexed reg arrays).
    int ws = 0; float wv = lv[0]; int wi = li[0];
#pragma unroll
    for (int j = 1; j < TOPK; ++j)
        if (better(wv, wi, lv[j], li[j])) { wv = lv[j]; wi = li[j]; ws = j; }
#pragma unroll
    for (int j = 0; j < TOPK; ++j)
        if (j == ws) { lv[j] = v; li[j] = ix; }
    mv = lv[0]; mi = li[0];
#pragma unroll
    for (int j = 1; j < TOPK; ++j)
        if (better(mv, mi, lv[j], li[j])) { mv = lv[j]; mi = li[j]; }
}

__device__ __forceinline__ void waveReduceTop10(float (&lv)[TOPK], int (&li)[TOPK],
                                                float* wcv, int* wci, int tid) {
    const int wave = tid >> 6;
    const int lane = tid & 63;
    for (int r = 0; r < TOPK; ++r) {
        float bv = lv[0]; int bi = li[0];
#pragma unroll
        for (int j = 1; j < TOPK; ++j)
            if (better(lv[j], li[j], bv, bi)) { bv = lv[j]; bi = li[j]; }
#pragma unroll
        for (int off = 32; off >= 1; off >>= 1) {
            float ov = __shfl_xor(bv, off, 64);
            int   oi = __shfl_xor(bi, off, 64);
            if (better(ov, oi, bv, bi)) { bv = ov; bi = oi; }
        }
        // winner lane invalidates its entry (flat indices are unique)
#pragma unroll
        for (int j = 0; j < TOPK; ++j)
            if (lv[j] == bv && li[j] == bi) { lv[j] = -2.0f; li[j] = 0x7fffffff; }
        if (lane == 0) { wcv[wave * TOPK + r] = bv; wci[wave * TOPK + r] = bi; }
    }
}

// 40 candidates in wcv/wci -> top-10, emitted through emit(r, v, i) by tid==0.
// Executed by the first wave only.
template <typename EmitFn>
__device__ __forceinline__ void wave0FinalTop10(const float* wcv, const int* wci,
                                                int tid, EmitFn emit) {
    float v = (tid < 40) ? wcv[tid] : -2.0f;
    int   ix = (tid < 40) ? wci[tid] : 0x7fffffff;
    for (int r = 0; r < TOPK; ++r) {
        float bv = v; int bi = ix;
#pragma unroll
        for (int off = 32; off >= 1; off >>= 1) {
            float ov = __shfl_xor(bv, off, 64);
            int   oi = __shfl_xor(bi, off, 64);
            if (better(ov, oi, bv, bi)) { bv = ov; bi = oi; }
        }
        if (v == bv && ix == bi) { v = -2.0f; ix = 0x7fffffff; }
        if (tid == 0) emit(r, bv, bi);
    }
}

__global__ __launch_bounds__(BLK) void iou_topk_kernel(
    const float4* __restrict__ prop, const float4* __restrict__ gt,
    float* __restrict__ iou_out, float* __restrict__ mask_out,
    float* __restrict__ cand_v, int* __restrict__ cand_i,
    int N, int M) {
    __shared__ float sbx1[MAXM], sby1[MAXM], sbx2[MAXM], sby2[MAXM], sAreaB[MAXM];
    __shared__ float4 pb[ROWS_PER_BLOCK];
    __shared__ float  sAreaA[ROWS_PER_BLOCK];
    __shared__ float wcv[4 * TOPK];
    __shared__ int   wci[4 * TOPK];

    const int tid = threadIdx.x;
    const int bid = blockIdx.x;
    const int row0 = bid * ROWS_PER_BLOCK;

    // stage gt boxes SoA (bank-conflict-free inner reads)
    for (int i = tid; i < M; i += BLK) {
        float4 b = gt[i];
        sbx1[i] = b.x; sby1[i] = b.y; sbx2[i] = b.z; sby2[i] = b.w;
        sAreaB[i] = __fmul_rn(b.z - b.x, b.w - b.y);
    }
    if (tid < ROWS_PER_BLOCK && row0 + tid < N) {
        float4 a = prop[row0 + tid];
        pb[tid] = a;
        sAreaA[tid] = __fmul_rn(a.z - a.x, a.w - a.y);
    }
    __syncthreads();

    float lv[TOPK]; int li[TOPK];
#pragma unroll
    for (int j = 0; j < TOPK; ++j) { lv[j] = -2.0f; li[j] = 0x7fffffff; }
    float mv = -2.0f; int mi = 0x7fffffff;

    for (int nl = 0; nl < ROWS_PER_BLOCK; ++nl) {
        const int row = row0 + nl;
        if (row >= N) break;
        const float4 a = pb[nl];
        const float  aA = sAreaA[nl];
        const long long rowbase = (long long)row * M;
        for (int m = tid; m < M; m += BLK) {
            const float ltx = fmaxf(a.x, sbx1[m]);
            const float lty = fmaxf(a.y, sby1[m]);
            const float rbx = fminf(a.z, sbx2[m]);
            const float rby = fminf(a.w, sby2[m]);
            const float w = fmaxf(rbx - ltx, 0.0f);
            const float h = fmaxf(rby - lty, 0.0f);
            const float inter = __fmul_rn(w, h);          // block FMA contraction
            const float s = aA + sAreaB[m];
            const float uni = s - inter;
            const float den = uni + 1e-8f;
            const float iou = inter / den;                // IEEE f32 divide
            const int gidx = (int)(rowbase + m);
            iou_out[rowbase + m] = iou;
            mask_out[rowbase + m] = 0.0f;
            if (better(iou, gidx, mv, mi)) insert10(lv, li, iou, gidx, mv, mi);
        }
    }

    waveReduceTop10(lv, li, wcv, wci, tid);
    __syncthreads();
    if (tid < 64) {
        wave0FinalTop10(wcv, wci, tid, [&](int r, float bv, int bi) {
            cand_v[bid * TOPK + r] = bv;
            cand_i[bid * TOPK + r] = bi;
        });
    }
}

__global__ __launch_bounds__(BLK) void topk_final_kernel(
    const float* __restrict__ cand_v, const int* __restrict__ cand_i,
    int ncand, float* __restrict__ mask_out) {
    __shared__ float wcv[4 * TOPK];
    __shared__ int   wci[4 * TOPK];
    const int tid = threadIdx.x;

    float lv[TOPK]; int li[TOPK];
#pragma unroll
    for (int j = 0; j < TOPK; ++j) { lv[j] = -2.0f; li[j] = 0x7fffffff; }
    float mv = -2.0f; int mi = 0x7fffffff;

    for (int i = tid; i < ncand; i += BLK) {
        float v = cand_v[i]; int ix = cand_i[i];
        if (better(v, ix, mv, mi)) insert10(lv, li, v, ix, mv, mi);
    }

    waveReduceTop10(lv, li, wcv, wci, tid);
    __syncthreads();
    if (tid < 64) {
        wave0FinalTop10(wcv, wci, tid, [&](int r, float bv, int bi) {
            (void)r;
            if (bi >= 0 && bi != 0x7fffffff && bv >= 0.0f) mask_out[bi] = 1.0f;
        });
    }
}

extern "C" void kernel_launch(void* const* d_in, const int* in_sizes, int n_in,
                              void* d_out, int out_size, void* d_ws, size_t ws_size,
                              hipStream_t stream) {
    const float4* prop = (const float4*)d_in[0];
    // d_in[1] = cls_prob (unused), d_in[3] = gt_cls (unused)
    const float4* gt = (const float4*)d_in[2];
    const int N = in_sizes[0] / 4;
    const int M = in_sizes[2] / 4;

    float* iou_out = (float*)d_out;
    float* mask_out = iou_out + (long long)N * M;

    const int nblocks = (N + ROWS_PER_BLOCK - 1) / ROWS_PER_BLOCK;
    float* cv = (float*)d_ws;
    int*   ci = (int*)((char*)d_ws + (size_t)nblocks * TOPK * sizeof(float));

    iou_topk_kernel<<<nblocks, BLK, 0, stream>>>(prop, gt, iou_out, mask_out,
                                                 cv, ci, N, M);
    topk_final_kernel<<<1, BLK, 0, stream>>>(cv, ci, nblocks * TOPK, mask_out);
}

// Round 2
// 94.338 us; speedup vs baseline: 3.0256x; 3.0256x over previous
//
#include <hip/hip_runtime.h>

#define TOPK 10
#define BLK 256
#define ROWS_PER_BLOCK 8
#define CAND_CAP 32768
#define SLACK 1e-5f

__device__ __forceinline__ bool better(float v1, int i1, float v2, int i2) {
    // top_k order: larger value first; ties broken by smaller flat index
    return (v1 > v2) || (v1 == v2 && i1 < i2);
}

__device__ __forceinline__ void insert10(float (&lv)[TOPK], int (&li)[TOPK],
                                         float v, int ix, float& mv, int& mi) {
    int ws = 0; float wv = lv[0]; int wi = li[0];
#pragma unroll
    for (int j = 1; j < TOPK; ++j)
        if (better(wv, wi, lv[j], li[j])) { wv = lv[j]; wi = li[j]; ws = j; }
#pragma unroll
    for (int j = 0; j < TOPK; ++j)
        if (j == ws) { lv[j] = v; li[j] = ix; }
    mv = lv[0]; mi = li[0];
#pragma unroll
    for (int j = 1; j < TOPK; ++j)
        if (better(mv, mi, lv[j], li[j])) { mv = lv[j]; mi = li[j]; }
}

__device__ __forceinline__ void waveReduceTop10(float (&lv)[TOPK], int (&li)[TOPK],
                                                float* wcv, int* wci, int tid) {
    const int wave = tid >> 6;
    const int lane = tid & 63;
    for (int r = 0; r < TOPK; ++r) {
        float bv = lv[0]; int bi = li[0];
#pragma unroll
        for (int j = 1; j < TOPK; ++j)
            if (better(lv[j], li[j], bv, bi)) { bv = lv[j]; bi = li[j]; }
#pragma unroll
        for (int off = 32; off >= 1; off >>= 1) {
            float ov = __shfl_xor(bv, off, 64);
            int   oi = __shfl_xor(bi, off, 64);
            if (better(ov, oi, bv, bi)) { bv = ov; bi = oi; }
        }
#pragma unroll
        for (int j = 0; j < TOPK; ++j)
            if (lv[j] == bv && li[j] == bi) { lv[j] = -2.0f; li[j] = 0x7fffffff; }
        if (lane == 0) { wcv[wave * TOPK + r] = bv; wci[wave * TOPK + r] = bi; }
    }
}

template <typename EmitFn>
__device__ __forceinline__ void wave0FinalTop10(const float* wcv, const int* wci,
                                                int tid, EmitFn emit) {
    float v = (tid < 40) ? wcv[tid] : -2.0f;
    int   ix = (tid < 40) ? wci[tid] : 0x7fffffff;
    for (int r = 0; r < TOPK; ++r) {
        float bv = v; int bi = ix;
#pragma unroll
        for (int off = 32; off >= 1; off >>= 1) {
            float ov = __shfl_xor(bv, off, 64);
            int   oi = __shfl_xor(bi, off, 64);
            if (better(ov, oi, bv, bi)) { bv = ov; bi = oi; }
        }
        if (v == bv && ix == bi) { v = -2.0f; ix = 0x7fffffff; }
        if (tid == 0) emit(r, bv, bi);
    }
}

// Exact IoU: identical op sequence to the round-1 kernel that matched numpy
// bitwise (absmax 0.0). No FMA contraction (__fmul_rn), IEEE f32 divide.
__device__ __forceinline__ float iou_exact(const float4 a, const float aA,
                                           const float4 b, const float bA) {
    const float ltx = fmaxf(a.x, b.x);
    const float lty = fmaxf(a.y, b.y);
    const float rbx = fminf(a.z, b.z);
    const float rby = fminf(a.w, b.w);
    const float w = fmaxf(rbx - ltx, 0.0f);
    const float h = fmaxf(rby - lty, 0.0f);
    const float inter = __fmul_rn(w, h);
    const float s = aA + bA;
    const float uni = s - inter;
    const float den = uni + 1e-8f;
    return inter / den;
}

// Approximate IoU for the threshold pre-pass: v_rcp_f32 (rel err ~1e-7,
// covered by SLACK=1e-5 in the threshold derivation).
__device__ __forceinline__ float iou_approx(const float4 a, const float aA,
                                            const float4 b, const float bA) {
    const float ltx = fmaxf(a.x, b.x);
    const float lty = fmaxf(a.y, b.y);
    const float rbx = fminf(a.z, b.z);
    const float rby = fminf(a.w, b.w);
    const float w = fmaxf(rbx - ltx, 0.0f);
    const float h = fmaxf(rby - lty, 0.0f);
    const float inter = __fmul_rn(w, h);
    const float den = (aA + bA - inter) + 1e-8f;
    return inter * __builtin_amdgcn_rcpf(den);
}

// K0: per-block max of approximate IoU. Compute-only (no big stores), no LDS
// in the main loop, gt boxes register-tiled 4-wide and reused across 8 rows.
__global__ __launch_bounds__(BLK) void blockmax_kernel(
    const float4* __restrict__ prop, const float4* __restrict__ gt,
    float* __restrict__ blockmax, int N, int M) {
    const int tid = threadIdx.x;
    const int bid = blockIdx.x;
    const int row0 = bid * ROWS_PER_BLOCK;
    const int M4 = M & ~3;
    float vmax = -2.0f;

    for (int m0 = 4 * tid; m0 < M4; m0 += 4 * BLK) {
        const float4 b0 = gt[m0 + 0], b1 = gt[m0 + 1], b2 = gt[m0 + 2], b3 = gt[m0 + 3];
        const float bA0 = __fmul_rn(b0.z - b0.x, b0.w - b0.y);
        const float bA1 = __fmul_rn(b1.z - b1.x, b1.w - b1.y);
        const float bA2 = __fmul_rn(b2.z - b2.x, b2.w - b2.y);
        const float bA3 = __fmul_rn(b3.z - b3.x, b3.w - b3.y);
#pragma unroll
        for (int nl = 0; nl < ROWS_PER_BLOCK; ++nl) {
            const int row = row0 + nl;
            if (row < N) {
                const float4 a = prop[row];                 // uniform -> SGPR
                const float aA = __fmul_rn(a.z - a.x, a.w - a.y);
                vmax = fmaxf(vmax, iou_approx(a, aA, b0, bA0));
                vmax = fmaxf(vmax, iou_approx(a, aA, b1, bA1));
                vmax = fmaxf(vmax, iou_approx(a, aA, b2, bA2));
                vmax = fmaxf(vmax, iou_approx(a, aA, b3, bA3));
            }
        }
    }
    for (int m = M4 + tid; m < M; m += BLK) {
        const float4 b = gt[m];
        const float bA = __fmul_rn(b.z - b.x, b.w - b.y);
#pragma unroll
        for (int nl = 0; nl < ROWS_PER_BLOCK; ++nl) {
            const int row = row0 + nl;
            if (row < N) {
                const float4 a = prop[row];
                const float aA = __fmul_rn(a.z - a.x, a.w - a.y);
                vmax = fmaxf(vmax, iou_approx(a, aA, b, bA));
            }
        }
    }

    __shared__ float sred[4];
#pragma unroll
    for (int off = 32; off >= 1; off >>= 1)
        vmax = fmaxf(vmax, __shfl_xor(vmax, off, 64));
    if ((tid & 63) == 0) sred[tid >> 6] = vmax;
    __syncthreads();
    if (tid == 0)
        blockmax[bid] = fmaxf(fmaxf(sred[0], sred[1]), fmaxf(sred[2], sred[3]));
}

// K2: T = (10th largest block max) - SLACK; zero candidate counter.
// Guarantees the exact global top-10 all have iou >= T.
__global__ __launch_bounds__(BLK) void threshold_kernel(
    const float* __restrict__ blockmax, int nb,
    float* __restrict__ tm_ptr, int* __restrict__ cand_cnt) {
    __shared__ float wcv[4 * TOPK];
    __shared__ int   wci[4 * TOPK];
    const int tid = threadIdx.x;

    float lv[TOPK]; int li[TOPK];
#pragma unroll
    for (int j = 0; j < TOPK; ++j) { lv[j] = -2.0f; li[j] = 0x7fffffff; }
    float mv = -2.0f; int mi = 0x7fffffff;

    for (int i = tid; i < nb; i += BLK) {
        const float v = blockmax[i];
        if (better(v, i, mv, mi)) insert10(lv, li, v, i, mv, mi);
    }
    waveReduceTop10(lv, li, wcv, wci, tid);
    __syncthreads();
    if (tid < 64) {
        wave0FinalTop10(wcv, wci, tid, [&](int r, float bv, int bi) {
            (void)bi;
            if (r == TOPK - 1) *tm_ptr = bv - SLACK;
        });
    }
    if (tid == 0) *cand_cnt = 0;
}

// K1: the store-bound main pass. Exact IoU, float4 stores, one compare per
// element against T; rare atomic append of candidate indices.
__global__ __launch_bounds__(BLK) void iou_main_kernel(
    const float4* __restrict__ prop, const float4* __restrict__ gt,
    float* __restrict__ iou_out, float* __restrict__ mask_out,
    const float* __restrict__ tm_ptr, int* __restrict__ cand_cnt,
    int* __restrict__ cand_idx, int N, int M) {
    const int tid = threadIdx.x;
    const int bid = blockIdx.x;
    const int row0 = bid * ROWS_PER_BLOCK;
    const float Tm = *tm_ptr;
    const int M4 = M & ~3;
    const float4 zero4 = make_float4(0.0f, 0.0f, 0.0f, 0.0f);

    for (int m0 = 4 * tid; m0 < M4; m0 += 4 * BLK) {
        const float4 b0 = gt[m0 + 0], b1 = gt[m0 + 1], b2 = gt[m0 + 2], b3 = gt[m0 + 3];
        const float bA0 = __fmul_rn(b0.z - b0.x, b0.w - b0.y);
        const float bA1 = __fmul_rn(b1.z - b1.x, b1.w - b1.y);
        const float bA2 = __fmul_rn(b2.z - b2.x, b2.w - b2.y);
        const float bA3 = __fmul_rn(b3.z - b3.x, b3.w - b3.y);
#pragma unroll
        for (int nl = 0; nl < ROWS_PER_BLOCK; ++nl) {
            const int row = row0 + nl;
            if (row < N) {
                const float4 a = prop[row];                 // uniform -> SGPR
                const float aA = __fmul_rn(a.z - a.x, a.w - a.y);
                const float i0 = iou_exact(a, aA, b0, bA0);
                const float i1 = iou_exact(a, aA, b1, bA1);
                const float i2 = iou_exact(a, aA, b2, bA2);
                const float i3 = iou_exact(a, aA, b3, bA3);
                const long long base = (long long)row * M + m0;
                *reinterpret_cast<float4*>(iou_out + base) = make_float4(i0, i1, i2, i3);
                *reinterpret_cast<float4*>(mask_out + base) = zero4;
                if (i0 >= Tm || i1 >= Tm || i2 >= Tm || i3 >= Tm) {  // rare
                    if (i0 >= Tm) { int s = atomicAdd(cand_cnt, 1); if (s < CAND_CAP) cand_idx[s] = (int)base; }
                    if (i1 >= Tm) { int s = atomicAdd(cand_cnt, 1); if (s < CAND_CAP) cand_idx[s] = (int)base + 1; }
                    if (i2 >= Tm) { int s = atomicAdd(cand_cnt, 1); if (s < CAND_CAP) cand_idx[s] = (int)base + 2; }
                    if (i3 >= Tm) { int s = atomicAdd(cand_cnt, 1); if (s < CAND_CAP) cand_idx[s] = (int)base + 3; }
                }
            }
        }
    }
    for (int m = M4 + tid; m < M; m += BLK) {
        const float4 b = gt[m];
        const float bA = __fmul_rn(b.z - b.x, b.w - b.y);
#pragma unroll
        for (int nl = 0; nl < ROWS_PER_BLOCK; ++nl) {
            const int row = row0 + nl;
            if (row < N) {
                const float4 a = prop[row];
                const float aA = __fmul_rn(a.z - a.x, a.w - a.y);
                const float v = iou_exact(a, aA, b, bA);
                const long long idx = (long long)row * M + m;
                iou_out[idx] = v;
                mask_out[idx] = 0.0f;
                if (v >= Tm) { int s = atomicAdd(cand_cnt, 1); if (s < CAND_CAP) cand_idx[s] = (int)idx; }
            }
        }
    }
}

// K4: exact top-10 of the (few) candidates; scatter ones into mask.
__global__ __launch_bounds__(BLK) void final_kernel(
    const int* __restrict__ cand_cnt, const int* __restrict__ cand_idx,
    const float* __restrict__ iou_out, float* __restrict__ mask_out) {
    __shared__ float wcv[4 * TOPK];
    __shared__ int   wci[4 * TOPK];
    const int tid = threadIdx.x;
    int c = *cand_cnt;
    if (c > CAND_CAP) c = CAND_CAP;

    float lv[TOPK]; int li[TOPK];
#pragma unroll
    for (int j = 0; j < TOPK; ++j) { lv[j] = -2.0f; li[j] = 0x7fffffff; }
    float mv = -2.0f; int mi = 0x7fffffff;

    for (int i = tid; i < c; i += BLK) {
        const int idx = cand_idx[i];
        const float v = iou_out[idx];
        if (better(v, idx, mv, mi)) insert10(lv, li, v, idx, mv, mi);
    }
    waveReduceTop10(lv, li, wcv, wci, tid);
    __syncthreads();
    if (tid < 64) {
        wave0FinalTop10(wcv, wci, tid, [&](int r, float bv, int bi) {
            (void)r;
            if (bi >= 0 && bi != 0x7fffffff && bv >= 0.0f) mask_out[bi] = 1.0f;
        });
    }
}

extern "C" void kernel_launch(void* const* d_in, const int* in_sizes, int n_in,
                              void* d_out, int out_size, void* d_ws, size_t ws_size,
                              hipStream_t stream) {
    const float4* prop = (const float4*)d_in[0];
    // d_in[1] = cls_prob (unused), d_in[3] = gt_cls (unused)
    const float4* gt = (const float4*)d_in[2];
    const int N = in_sizes[0] / 4;
    const int M = in_sizes[2] / 4;

    float* iou_out = (float*)d_out;
    float* mask_out = iou_out + (long long)N * M;

    const int nblocks = (N + ROWS_PER_BLOCK - 1) / ROWS_PER_BLOCK;

    // ws layout: blockmax[nblocks] @0 | Tm @16K | cnt @16K+4 | cand @16K+8
    char* ws = (char*)d_ws;
    float* blockmax = (float*)ws;
    float* tm_ptr = (float*)(ws + 16384);
    int* cand_cnt = (int*)(ws + 16388);
    int* cand_idx = (int*)(ws + 16392);

    blockmax_kernel<<<nblocks, BLK, 0, stream>>>(prop, gt, blockmax, N, M);
    threshold_kernel<<<1, BLK, 0, stream>>>(blockmax, nblocks, tm_ptr, cand_cnt);
    iou_main_kernel<<<nblocks, BLK, 0, stream>>>(prop, gt, iou_out, mask_out,
                                                 tm_ptr, cand_cnt, cand_idx, N, M);
    final_kernel<<<1, BLK, 0, stream>>>(cand_cnt, cand_idx, iou_out, mask_out);
}

// Round 3
// 86.906 us; speedup vs baseline: 3.2843x; 1.0855x over previous
//
#include <hip/hip_runtime.h>

#define TOPK 10
#define BLK 256
#define ROWS_PER_BLOCK 8
#define CAND_CAP 32768
#define SLACK 1e-5f

__device__ __forceinline__ bool better(float v1, int i1, float v2, int i2) {
    // top_k order: larger value first; ties broken by smaller flat index
    return (v1 > v2) || (v1 == v2 && i1 < i2);
}

__device__ __forceinline__ void insert10(float (&lv)[TOPK], int (&li)[TOPK],
                                         float v, int ix, float& mv, int& mi) {
    int ws = 0; float wv = lv[0]; int wi = li[0];
#pragma unroll
    for (int j = 1; j < TOPK; ++j)
        if (better(wv, wi, lv[j], li[j])) { wv = lv[j]; wi = li[j]; ws = j; }
#pragma unroll
    for (int j = 0; j < TOPK; ++j)
        if (j == ws) { lv[j] = v; li[j] = ix; }
    mv = lv[0]; mi = li[0];
#pragma unroll
    for (int j = 1; j < TOPK; ++j)
        if (better(mv, mi, lv[j], li[j])) { mv = lv[j]; mi = li[j]; }
}

__device__ __forceinline__ void waveReduceTop10(float (&lv)[TOPK], int (&li)[TOPK],
                                                float* wcv, int* wci, int tid) {
    const int wave = tid >> 6;
    const int lane = tid & 63;
    for (int r = 0; r < TOPK; ++r) {
        float bv = lv[0]; int bi = li[0];
#pragma unroll
        for (int j = 1; j < TOPK; ++j)
            if (better(lv[j], li[j], bv, bi)) { bv = lv[j]; bi = li[j]; }
#pragma unroll
        for (int off = 32; off >= 1; off >>= 1) {
            float ov = __shfl_xor(bv, off, 64);
            int   oi = __shfl_xor(bi, off, 64);
            if (better(ov, oi, bv, bi)) { bv = ov; bi = oi; }
        }
#pragma unroll
        for (int j = 0; j < TOPK; ++j)
            if (lv[j] == bv && li[j] == bi) { lv[j] = -2.0f; li[j] = 0x7fffffff; }
        if (lane == 0) { wcv[wave * TOPK + r] = bv; wci[wave * TOPK + r] = bi; }
    }
}

template <typename EmitFn>
__device__ __forceinline__ void wave0FinalTop10(const float* wcv, const int* wci,
                                                int tid, EmitFn emit) {
    float v = (tid < 40) ? wcv[tid] : -2.0f;
    int   ix = (tid < 40) ? wci[tid] : 0x7fffffff;
    for (int r = 0; r < TOPK; ++r) {
        float bv = v; int bi = ix;
#pragma unroll
        for (int off = 32; off >= 1; off >>= 1) {
            float ov = __shfl_xor(bv, off, 64);
            int   oi = __shfl_xor(bi, off, 64);
            if (better(ov, oi, bv, bi)) { bv = ov; bi = oi; }
        }
        if (v == bv && ix == bi) { v = -2.0f; ix = 0x7fffffff; }
        if (tid == 0) emit(r, bv, bi);
    }
}

// Exact IoU: identical op sequence to the round-1 kernel that matched numpy
// bitwise (absmax 0.0). No FMA contraction (__fmul_rn), IEEE f32 divide.
__device__ __forceinline__ float iou_exact(const float4 a, const float aA,
                                           const float4 b, const float bA) {
    const float ltx = fmaxf(a.x, b.x);
    const float lty = fmaxf(a.y, b.y);
    const float rbx = fminf(a.z, b.z);
    const float rby = fminf(a.w, b.w);
    const float w = fmaxf(rbx - ltx, 0.0f);
    const float h = fmaxf(rby - lty, 0.0f);
    const float inter = __fmul_rn(w, h);
    const float s = aA + bA;
    const float uni = s - inter;
    const float den = uni + 1e-8f;
    return inter / den;
}

// Approximate IoU for the threshold sampling pass: v_rcp_f32 (rel err ~1e-7,
// covered by SLACK=1e-5 in the threshold derivation).
__device__ __forceinline__ float iou_approx(const float4 a, const float aA,
                                            const float4 b, const float bA) {
    const float ltx = fmaxf(a.x, b.x);
    const float lty = fmaxf(a.y, b.y);
    const float rbx = fminf(a.z, b.z);
    const float rby = fminf(a.w, b.w);
    const float w = fmaxf(rbx - ltx, 0.0f);
    const float h = fmaxf(rby - lty, 0.0f);
    const float inter = __fmul_rn(w, h);
    const float den = (aA + bA - inter) + 1e-8f;
    return inter * __builtin_amdgcn_rcpf(den);
}

// K0': SAMPLED max-sketch. One approx-IoU sample per thread (block's own 8
// rows x 32 strided cols, column phase varies per block) -> per-block max.
// Validity: min of any 10 distinct elements <= global 10th-largest, so the
// 10th-largest of these maxes (minus slack) is a correct lower bound.
// Replaces the round-2 full N*M pre-pass (~25-30 us) with ~2 us.
__global__ __launch_bounds__(BLK) void sample_max_kernel(
    const float4* __restrict__ prop, const float4* __restrict__ gt,
    float* __restrict__ blockmax, int N, int M) {
    const int tid = threadIdx.x;
    const int bid = blockIdx.x;
    const int row = bid * ROWS_PER_BLOCK + (tid & 7);
    // 32 columns per block, evenly strided, phase-shifted by block id
    long long c = ((long long)(tid >> 3) * M) >> 5;
    const int col = (int)((c + (bid & 63)) % M);

    float v = -2.0f;
    if (row < N) {
        const float4 a = prop[row];
        const float aA = __fmul_rn(a.z - a.x, a.w - a.y);
        const float4 b = gt[col];
        const float bA = __fmul_rn(b.z - b.x, b.w - b.y);
        v = iou_approx(a, aA, b, bA);
    }

    __shared__ float sred[4];
#pragma unroll
    for (int off = 32; off >= 1; off >>= 1)
        v = fmaxf(v, __shfl_xor(v, off, 64));
    if ((tid & 63) == 0) sred[tid >> 6] = v;
    __syncthreads();
    if (tid == 0)
        blockmax[bid] = fmaxf(fmaxf(sred[0], sred[1]), fmaxf(sred[2], sred[3]));
}

// K2: T = (10th largest sampled block max) - SLACK; zero candidate counter.
__global__ __launch_bounds__(BLK) void threshold_kernel(
    const float* __restrict__ blockmax, int nb,
    float* __restrict__ tm_ptr, int* __restrict__ cand_cnt) {
    __shared__ float wcv[4 * TOPK];
    __shared__ int   wci[4 * TOPK];
    const int tid = threadIdx.x;

    float lv[TOPK]; int li[TOPK];
#pragma unroll
    for (int j = 0; j < TOPK; ++j) { lv[j] = -2.0f; li[j] = 0x7fffffff; }
    float mv = -2.0f; int mi = 0x7fffffff;

    for (int i = tid; i < nb; i += BLK) {
        const float v = blockmax[i];
        if (better(v, i, mv, mi)) insert10(lv, li, v, i, mv, mi);
    }
    waveReduceTop10(lv, li, wcv, wci, tid);
    __syncthreads();
    if (tid < 64) {
        wave0FinalTop10(wcv, wci, tid, [&](int r, float bv, int bi) {
            (void)bi;
            if (r == TOPK - 1) *tm_ptr = bv - SLACK;
        });
    }
    if (tid == 0) *cand_cnt = 0;
}

// K1: the store-bound main pass. Exact IoU, float4 stores, one compare per
// element against T; rare atomic append of candidate indices.
__global__ __launch_bounds__(BLK) void iou_main_kernel(
    const float4* __restrict__ prop, const float4* __restrict__ gt,
    float* __restrict__ iou_out, float* __restrict__ mask_out,
    const float* __restrict__ tm_ptr, int* __restrict__ cand_cnt,
    int* __restrict__ cand_idx, int N, int M) {
    const int tid = threadIdx.x;
    const int bid = blockIdx.x;
    const int row0 = bid * ROWS_PER_BLOCK;
    const float Tm = *tm_ptr;
    const int M4 = M & ~3;
    const float4 zero4 = make_float4(0.0f, 0.0f, 0.0f, 0.0f);

    for (int m0 = 4 * tid; m0 < M4; m0 += 4 * BLK) {
        const float4 b0 = gt[m0 + 0], b1 = gt[m0 + 1], b2 = gt[m0 + 2], b3 = gt[m0 + 3];
        const float bA0 = __fmul_rn(b0.z - b0.x, b0.w - b0.y);
        const float bA1 = __fmul_rn(b1.z - b1.x, b1.w - b1.y);
        const float bA2 = __fmul_rn(b2.z - b2.x, b2.w - b2.y);
        const float bA3 = __fmul_rn(b3.z - b3.x, b3.w - b3.y);
#pragma unroll
        for (int nl = 0; nl < ROWS_PER_BLOCK; ++nl) {
            const int row = row0 + nl;
            if (row < N) {
                const float4 a = prop[row];                 // uniform -> SGPR
                const float aA = __fmul_rn(a.z - a.x, a.w - a.y);
                const float i0 = iou_exact(a, aA, b0, bA0);
                const float i1 = iou_exact(a, aA, b1, bA1);
                const float i2 = iou_exact(a, aA, b2, bA2);
                const float i3 = iou_exact(a, aA, b3, bA3);
                const long long base = (long long)row * M + m0;
                *reinterpret_cast<float4*>(iou_out + base) = make_float4(i0, i1, i2, i3);
                *reinterpret_cast<float4*>(mask_out + base) = zero4;
                if (i0 >= Tm || i1 >= Tm || i2 >= Tm || i3 >= Tm) {  // rare
                    if (i0 >= Tm) { int s = atomicAdd(cand_cnt, 1); if (s < CAND_CAP) cand_idx[s] = (int)base; }
                    if (i1 >= Tm) { int s = atomicAdd(cand_cnt, 1); if (s < CAND_CAP) cand_idx[s] = (int)base + 1; }
                    if (i2 >= Tm) { int s = atomicAdd(cand_cnt, 1); if (s < CAND_CAP) cand_idx[s] = (int)base + 2; }
                    if (i3 >= Tm) { int s = atomicAdd(cand_cnt, 1); if (s < CAND_CAP) cand_idx[s] = (int)base + 3; }
                }
            }
        }
    }
    for (int m = M4 + tid; m < M; m += BLK) {
        const float4 b = gt[m];
        const float bA = __fmul_rn(b.z - b.x, b.w - b.y);
#pragma unroll
        for (int nl = 0; nl < ROWS_PER_BLOCK; ++nl) {
            const int row = row0 + nl;
            if (row < N) {
                const float4 a = prop[row];
                const float aA = __fmul_rn(a.z - a.x, a.w - a.y);
                const float v = iou_exact(a, aA, b, bA);
                const long long idx = (long long)row * M + m;
                iou_out[idx] = v;
                mask_out[idx] = 0.0f;
                if (v >= Tm) { int s = atomicAdd(cand_cnt, 1); if (s < CAND_CAP) cand_idx[s] = (int)idx; }
            }
        }
    }
}

// K4: exact top-10 of the (few) candidates; scatter ones into mask.
__global__ __launch_bounds__(BLK) void final_kernel(
    const int* __restrict__ cand_cnt, const int* __restrict__ cand_idx,
    const float* __restrict__ iou_out, float* __restrict__ mask_out) {
    __shared__ float wcv[4 * TOPK];
    __shared__ int   wci[4 * TOPK];
    const int tid = threadIdx.x;
    int c = *cand_cnt;
    if (c > CAND_CAP) c = CAND_CAP;

    float lv[TOPK]; int li[TOPK];
#pragma unroll
    for (int j = 0; j < TOPK; ++j) { lv[j] = -2.0f; li[j] = 0x7fffffff; }
    float mv = -2.0f; int mi = 0x7fffffff;

    for (int i = tid; i < c; i += BLK) {
        const int idx = cand_idx[i];
        const float v = iou_out[idx];
        if (better(v, idx, mv, mi)) insert10(lv, li, v, idx, mv, mi);
    }
    waveReduceTop10(lv, li, wcv, wci, tid);
    __syncthreads();
    if (tid < 64) {
        wave0FinalTop10(wcv, wci, tid, [&](int r, float bv, int bi) {
            (void)r;
            if (bi >= 0 && bi != 0x7fffffff && bv >= 0.0f) mask_out[bi] = 1.0f;
        });
    }
}

extern "C" void kernel_launch(void* const* d_in, const int* in_sizes, int n_in,
                              void* d_out, int out_size, void* d_ws, size_t ws_size,
                              hipStream_t stream) {
    const float4* prop = (const float4*)d_in[0];
    // d_in[1] = cls_prob (unused), d_in[3] = gt_cls (unused)
    const float4* gt = (const float4*)d_in[2];
    const int N = in_sizes[0] / 4;
    const int M = in_sizes[2] / 4;

    float* iou_out = (float*)d_out;
    float* mask_out = iou_out + (long long)N * M;

    const int nblocks = (N + ROWS_PER_BLOCK - 1) / ROWS_PER_BLOCK;

    // ws layout: blockmax[nblocks] @0 | Tm @16K | cnt @16K+4 | cand @16K+8
    char* ws = (char*)d_ws;
    float* blockmax = (float*)ws;
    float* tm_ptr = (float*)(ws + 16384);
    int* cand_cnt = (int*)(ws + 16388);
    int* cand_idx = (int*)(ws + 16392);

    sample_max_kernel<<<nblocks, BLK, 0, stream>>>(prop, gt, blockmax, N, M);
    threshold_kernel<<<1, BLK, 0, stream>>>(blockmax, nblocks, tm_ptr, cand_cnt);
    iou_main_kernel<<<nblocks, BLK, 0, stream>>>(prop, gt, iou_out, mask_out,
                                                 tm_ptr, cand_cnt, cand_idx, N, M);
    final_kernel<<<1, BLK, 0, stream>>>(cand_cnt, cand_idx, iou_out, mask_out);
}